// Round 5
// baseline (104.542 us; speedup 1.0000x reference)
//
#include <hip/hip_runtime.h>
#include <stdint.h>
#include <math.h>

#define T_SEQ 8192

typedef int vint4 __attribute__((ext_vector_type(4)));  // native vector: OK for nontemporal builtins

__device__ __forceinline__ uint32_t rotl32(uint32_t x, int n) {
    return (x << n) | (x >> (32 - n));
}

// JAX threefry2x32 with key = (0, 42) (jax.random.key(42)), counts = iota(12288)
// split in half: pair i -> (x0=i, x1=i+6144); bits[idx] = idx<6144 ? y0 : y1.
__device__ uint32_t jax_threefry_bits_12288(uint32_t idx) {
    const uint32_t k0 = 0u, k1 = 42u, k2 = 0u ^ 42u ^ 0x1BD11BDAu;
    uint32_t i = (idx < 6144u) ? idx : (idx - 6144u);
    uint32_t x0 = i + k0;
    uint32_t x1 = (i + 6144u) + k1;
#define TF_R4(a,b,c,d) \
    x0 += x1; x1 = rotl32(x1, a); x1 ^= x0; \
    x0 += x1; x1 = rotl32(x1, b); x1 ^= x0; \
    x0 += x1; x1 = rotl32(x1, c); x1 ^= x0; \
    x0 += x1; x1 = rotl32(x1, d); x1 ^= x0;
    TF_R4(13, 15, 26, 6);   x0 += k1; x1 += k2 + 1u;
    TF_R4(17, 29, 16, 24);  x0 += k2; x1 += k0 + 2u;
    TF_R4(13, 15, 26, 6);   x0 += k0; x1 += k1 + 3u;
    TF_R4(17, 29, 16, 24);  x0 += k1; x1 += k2 + 4u;
    TF_R4(13, 15, 26, 6);   x0 += k2; x1 += k0 + 5u;
#undef TF_R4
    return (idx < 6144u) ? x0 : x1;
}

// Fully fused stats + 2-layer MLP. 4 rows/block, 512 threads (8 waves), 256 blocks
// = 1 block/CU. Waves {2r,2r+1} serve row r. Per-wave privatized histograms.
__global__ __launch_bounds__(512) void fused_kernel(const int* __restrict__ tok,
                                                    const float* __restrict__ W1,
                                                    const float* __restrict__ b1,
                                                    const float* __restrict__ W2,
                                                    const float* __restrict__ b2,
                                                    float* __restrict__ out) {
    const int tid = threadIdx.x;
    const int wave = tid >> 6;
    const int r0 = blockIdx.x * 4;

    __shared__ int hist[8][128];
    __shared__ int wsum[8];
    __shared__ unsigned wsq[8];
    __shared__ float s[4][150];  // stats rows
    __shared__ float h[4][256];  // hidden layer

    // zero histograms (1024 ints, 2 per thread)
    for (int i = tid; i < 1024; i += 512) ((int*)hist)[i] = 0;
    __syncthreads();

    // ---- phase 1: token stream -> hist / sum / sumsq ----
    {
        const int row_local = tid >> 7;   // 0..3 (== wave>>1)
        const int t128 = tid & 127;       // thread id within the row's 128-thread group
        const vint4* tp = (const vint4*)(tok + (size_t)(r0 + row_local) * T_SEQ);
        int sum = 0;
        unsigned sq = 0;
#pragma unroll
        for (int j = 0; j < 16; ++j) {
            vint4 v = __builtin_nontemporal_load(&tp[j * 128 + t128]); // single-use stream
            atomicAdd(&hist[wave][v.x & 127], 1); sum += v.x; sq += (unsigned)__mul24(v.x, v.x);
            atomicAdd(&hist[wave][v.y & 127], 1); sum += v.y; sq += (unsigned)__mul24(v.y, v.y);
            atomicAdd(&hist[wave][v.z & 127], 1); sum += v.z; sq += (unsigned)__mul24(v.z, v.z);
            atomicAdd(&hist[wave][v.w & 127], 1); sum += v.w; sq += (unsigned)__mul24(v.w, v.w);
        }
        // 64-lane wave reduction; per-wave sums cover 4096 tokens:
        // sum <= 4096*389 ~ 1.6e6, sq <= 4096*389^2 ~ 6.2e8 — both fit in 32 bits
#pragma unroll
        for (int off = 32; off > 0; off >>= 1) {
            sum += __shfl_down(sum, off);
            sq  += __shfl_down(sq, off);
        }
        if ((tid & 63) == 0) { wsum[wave] = sum; wsq[wave] = sq; }
    }
    __syncthreads();

    // ---- stats assembly into LDS (600 slots: 4 rows x 150 dims; 512 threads,
    // so stride the loop — first 88 threads take a second slot) ----
    for (int i = tid; i < 600; i += 512) {
        const int r = i / 150;
        const int k = i - r * 150;
        const int wb = r * 2;
        float val;
        if (k < 128) {
            int hh = hist[wb][k] + hist[wb + 1][k];
            // reference divisor (8192.0f + 1e-8f) == 8192.0f exactly in fp32
            val = (float)hh * (1.0f / 8192.0f);
        } else if (k == 128) {
            int ss = wsum[wb] + wsum[wb + 1];
            val = (float)ss * (1.0f / 8192.0f);  // exact: ss < 2^24, / 2^13
        } else if (k == 129) {
            double ss = (double)(wsum[wb] + wsum[wb + 1]);
            double qq = (double)wsq[wb] + (double)wsq[wb + 1];
            val = (float)sqrt((qq - ss * ss / 8192.0) / 8191.0);  // unbiased (T-1)
        } else if (k < 138) {
            val = 0.0f;  // rhythm dims 2..9
        } else {
            uint32_t bits = jax_threefry_bits_12288((uint32_t)(r0 + r) * 12u + (uint32_t)(k - 138));
            val = __uint_as_float((bits >> 9) | 0x3f800000u) - 1.0f;
        }
        s[r][k] = val;
    }
    __syncthreads();

    // ---- phase 2: layer 1 (512 threads = 2 row-pairs x 256 cols) ----
    {
        const int g = tid >> 8, c = tid & 255;   // g: rows {2g, 2g+1}
        float a0 = b1[c], a1 = a0;
#pragma unroll 5
        for (int k = 0; k < 150; ++k) {
            float w = W1[k * 256 + c];           // coalesced; both halves hit L1
            a0 = fmaf(s[2 * g][k], w, a0);       // s: wave-uniform broadcast
            a1 = fmaf(s[2 * g + 1][k], w, a1);
        }
        h[2 * g][c] = fmaxf(a0, 0.0f);
        h[2 * g + 1][c] = fmaxf(a1, 0.0f);
    }
    __syncthreads();

    // ---- phase 3: layer 2 (512 threads = 4 rows x 128 cols) ----
    {
        const int r = tid >> 7, c = tid & 127;
        const float* hr = h[r];
        float acc = b2[c];
#pragma unroll 8
        for (int k = 0; k < 256; ++k)
            acc = fmaf(hr[k], W2[k * 128 + c], acc);  // hr broadcast, W2 coalesced
        out[(r0 + r) * 128 + c] = acc;
    }
}

extern "C" void kernel_launch(void* const* d_in, const int* in_sizes, int n_in,
                              void* d_out, int out_size, void* d_ws, size_t ws_size,
                              hipStream_t stream) {
    const int*   tok = (const int*)d_in[0];
    const float* W1  = (const float*)d_in[1];
    const float* b1  = (const float*)d_in[2];
    const float* W2  = (const float*)d_in[3];
    const float* b2  = (const float*)d_in[4];
    float* out = (float*)d_out;

    fused_kernel<<<256, 512, 0, stream>>>(tok, W1, b1, W2, b2, out);
}

// Round 6
// 98.255 us; speedup vs baseline: 1.0640x; 1.0640x over previous
//
#include <hip/hip_runtime.h>
#include <stdint.h>
#include <math.h>

#define T_SEQ 8192

typedef int vint4 __attribute__((ext_vector_type(4)));  // native vector: OK for nontemporal builtins

__device__ __forceinline__ uint32_t rotl32(uint32_t x, int n) {
    return (x << n) | (x >> (32 - n));
}

// JAX threefry2x32 with key = (0, 42) (jax.random.key(42)), counts = iota(12288)
// split in half: pair i -> (x0=i, x1=i+6144); bits[idx] = idx<6144 ? y0 : y1.
__device__ uint32_t jax_threefry_bits_12288(uint32_t idx) {
    const uint32_t k0 = 0u, k1 = 42u, k2 = 0u ^ 42u ^ 0x1BD11BDAu;
    uint32_t i = (idx < 6144u) ? idx : (idx - 6144u);
    uint32_t x0 = i + k0;
    uint32_t x1 = (i + 6144u) + k1;
#define TF_R4(a,b,c,d) \
    x0 += x1; x1 = rotl32(x1, a); x1 ^= x0; \
    x0 += x1; x1 = rotl32(x1, b); x1 ^= x0; \
    x0 += x1; x1 = rotl32(x1, c); x1 ^= x0; \
    x0 += x1; x1 = rotl32(x1, d); x1 ^= x0;
    TF_R4(13, 15, 26, 6);   x0 += k1; x1 += k2 + 1u;
    TF_R4(17, 29, 16, 24);  x0 += k2; x1 += k0 + 2u;
    TF_R4(13, 15, 26, 6);   x0 += k0; x1 += k1 + 3u;
    TF_R4(17, 29, 16, 24);  x0 += k1; x1 += k2 + 4u;
    TF_R4(13, 15, 26, 6);   x0 += k2; x1 += k0 + 5u;
#undef TF_R4
    return (idx < 6144u) ? x0 : x1;
}

// Fully fused: stats + 2-layer MLP. 2 rows per block, 512 threads (8 waves),
// 512 blocks = 2 blocks/CU = 16 waves/CU (measured-best config: R3, 98.5us).
// Waves 0-3 -> row r0, waves 4-7 -> row r0+1. Per-wave privatized histograms.
__global__ __launch_bounds__(512) void fused_kernel(const int* __restrict__ tok,
                                                    const float* __restrict__ W1,
                                                    const float* __restrict__ b1,
                                                    const float* __restrict__ W2,
                                                    const float* __restrict__ b2,
                                                    float* __restrict__ out) {
    const int tid = threadIdx.x;
    const int wave = tid >> 6;
    const int r0 = blockIdx.x * 2;

    __shared__ int hist[8][128];
    __shared__ int wsum[8];
    __shared__ unsigned wsq[8];
    __shared__ float s[2][150];    // stats rows
    __shared__ float h[2][256];    // hidden layer
    __shared__ float part[2][128]; // layer-2 split-k partials (upper half)

    // zero histograms (1024 ints, 2 per thread)
    for (int i = tid; i < 1024; i += 512) ((int*)hist)[i] = 0;
    __syncthreads();

    // ---- phase 1: token stream -> hist / sum / sumsq ----
    {
        const int row_local = tid >> 8;   // 0 or 1
        const int t256 = tid & 255;       // thread id within the row's 256-thread group
        const vint4* tp = (const vint4*)(tok + (size_t)(r0 + row_local) * T_SEQ);
        int sum = 0;
        unsigned sq = 0;
#pragma unroll
        for (int j = 0; j < 8; ++j) {
            vint4 v = __builtin_nontemporal_load(&tp[j * 256 + t256]); // single-use stream
            atomicAdd(&hist[wave][v.x & 127], 1); sum += v.x; sq += (unsigned)__mul24(v.x, v.x);
            atomicAdd(&hist[wave][v.y & 127], 1); sum += v.y; sq += (unsigned)__mul24(v.y, v.y);
            atomicAdd(&hist[wave][v.z & 127], 1); sum += v.z; sq += (unsigned)__mul24(v.z, v.z);
            atomicAdd(&hist[wave][v.w & 127], 1); sum += v.w; sq += (unsigned)__mul24(v.w, v.w);
        }
        // 64-lane wave reduction; both sums fit in 32 bits (max sumsq ~1.25e9 < 2^31)
#pragma unroll
        for (int off = 32; off > 0; off >>= 1) {
            sum += __shfl_down(sum, off);
            sq  += __shfl_down(sq, off);
        }
        if ((tid & 63) == 0) { wsum[wave] = sum; wsq[wave] = sq; }
    }
    __syncthreads();

    // ---- stats assembly into LDS (300 active threads: 2 rows x 150 dims) ----
    if (tid < 300) {
        const int r = tid >= 150;
        const int k = tid - r * 150;
        const int wb = r * 4;
        float val;
        if (k < 128) {
            int hh = hist[wb][k] + hist[wb + 1][k] + hist[wb + 2][k] + hist[wb + 3][k];
            // reference divisor (8192.0f + 1e-8f) == 8192.0f exactly in fp32
            val = (float)hh * (1.0f / 8192.0f);
        } else if (k == 128) {
            int ss = wsum[wb] + wsum[wb + 1] + wsum[wb + 2] + wsum[wb + 3];
            val = (float)ss * (1.0f / 8192.0f);  // exact: ss < 2^24, / 2^13
        } else if (k == 129) {
            double ss = (double)(wsum[wb] + wsum[wb + 1] + wsum[wb + 2] + wsum[wb + 3]);
            double qq = (double)wsq[wb] + (double)wsq[wb + 1] + (double)wsq[wb + 2] + (double)wsq[wb + 3];
            val = (float)sqrt((qq - ss * ss / 8192.0) / 8191.0);  // unbiased (T-1)
        } else if (k < 138) {
            val = 0.0f;  // rhythm dims 2..9
        } else {
            uint32_t bits = jax_threefry_bits_12288((uint32_t)(r0 + r) * 12u + (uint32_t)(k - 138));
            val = __uint_as_float((bits >> 9) | 0x3f800000u) - 1.0f;
        }
        s[r][k] = val;
    }
    __syncthreads();

    // ---- phase 2: layer 1 (512 threads = 2 rows x 256 cols) ----
    {
        const int g = tid >> 8, c = tid & 255;
        float acc = b1[c];
#pragma unroll 5
        for (int k = 0; k < 150; ++k)
            acc = fmaf(s[g][k], W1[k * 256 + c], acc);  // s broadcast, W1 coalesced
        h[g][c] = fmaxf(acc, 0.0f);
    }
    __syncthreads();

    // ---- phase 3: layer 2, split-k over 2 halves (512 threads = 2x2x128) ----
    {
        const int half = tid >> 8, g = (tid >> 7) & 1, c = tid & 127;
        const float* hr = h[g];
        const int kb = half * 128;
        float acc = half ? 0.0f : b2[c];
#pragma unroll 8
        for (int k = 0; k < 128; ++k)
            acc = fmaf(hr[kb + k], W2[(kb + k) * 128 + c], acc);
        if (half) part[g][c] = acc;
        __syncthreads();
        if (!half) out[(r0 + g) * 128 + c] = acc + part[g][c];
    }
}

extern "C" void kernel_launch(void* const* d_in, const int* in_sizes, int n_in,
                              void* d_out, int out_size, void* d_ws, size_t ws_size,
                              hipStream_t stream) {
    const int*   tok = (const int*)d_in[0];
    const float* W1  = (const float*)d_in[1];
    const float* b1  = (const float*)d_in[2];
    const float* W2  = (const float*)d_in[3];
    const float* b2  = (const float*)d_in[4];
    float* out = (float*)d_out;

    fused_kernel<<<512, 512, 0, stream>>>(tok, W1, b1, W2, b2, out);
}